// Round 1
// baseline (1287.953 us; speedup 1.0000x reference)
//
#include <hip/hip_runtime.h>
#include <hip/hip_cooperative_groups.h>
#include <cstdint>

namespace cg = cooperative_groups;

#define TT 1024
#define VV 50257

static constexpr float W_ECR = 100.0f;
static constexpr int   MAX_ITER = 100;
static constexpr float STOPTHR = 0.005f;
static constexpr float EPSF = 1e-16f;
// exp(-20*m) = exp2(m * (-20*log2(e)))
static constexpr float C2 = -28.853900817779268f;

__device__ __forceinline__ float blockReduceSum(float val, float* sred) {
    // wave (64-lane) reduction
    #pragma unroll
    for (int off = 32; off > 0; off >>= 1)
        val += __shfl_down(val, off, 64);
    const int lane = threadIdx.x & 63;
    const int wid  = threadIdx.x >> 6;
    if (lane == 0) sred[wid] = val;
    __syncthreads();
    float r = (threadIdx.x < (blockDim.x >> 6)) ? sred[threadIdx.x] : 0.0f;
    if (wid == 0) {
        r += __shfl_down(r, 2, 64);
        r += __shfl_down(r, 1, 64);
    }
    __syncthreads();   // allow sred reuse by caller
    return r;          // valid in thread 0 only
}

// Phase A: ktu[j] += sum_t exp(-20*M[t][j]) * u[t]   (column reduction, atomics)
__device__ __forceinline__ void phaseA(const float* __restrict__ M,
                                       const float* __restrict__ u,
                                       float* __restrict__ ktu,
                                       int gtid, int nthr) {
    constexpr int TCH = 32;            // rows per work item
    constexpr int NCH = TT / TCH;      // 32 chunks
    const unsigned nitems = (unsigned)VV * NCH;   // 1,608,224
    for (unsigned it = (unsigned)gtid; it < nitems; it += (unsigned)nthr) {
        const unsigned c = it / VV;            // constant divisor -> magic mul
        const unsigned j = it - c * VV;
        const float* p  = M + (size_t)(c * TCH) * VV + j;
        const float* up = u + c * TCH;
        float s = 0.0f;
        #pragma unroll 8
        for (int i = 0; i < TCH; ++i) {
            s += exp2f(p[(size_t)i * VV] * C2) * up[i];
        }
        atomicAdd(&ktu[j], s);
    }
}

__global__ __launch_bounds__(256)
void sinkhorn_ot_kernel(const float* __restrict__ M,
                        float* __restrict__ ws,
                        float* __restrict__ out) {
    cg::grid_group grid = cg::this_grid();

    float* ktu  = ws;                    // VV
    float* v    = ws + VV;               // VV
    float* u    = ws + 2 * VV;           // TT
    float* scal = ws + 2 * VV + TT;      // [0]=err accum, [1]=loss accum

    const int tid  = threadIdx.x;
    const int gtid = blockIdx.x * blockDim.x + tid;
    const int nthr = gridDim.x * blockDim.x;

    __shared__ float sred[8];
    __shared__ float sbc;

    const float a_ = 1.0f / TT;
    const float b_ = 1.0f / VV;

    // ---- init (ws is poisoned 0xAA before every call) ----
    for (int j = gtid; j < VV; j += nthr) ktu[j] = 0.0f;
    for (int t = gtid; t < TT; t += nthr) u[t] = a_;
    if (gtid == 0) { scal[0] = 0.0f; scal[1] = 0.0f; }
    grid.sync();

    bool haveKtu = false;
    int  cpt = 0;
    while (true) {
        // ---- phase A: ktu = K^T u ----
        if (!haveKtu) {
            phaseA(M, u, ktu, gtid, nthr);
            grid.sync();
        }
        haveKtu = false;

        // ---- phase V: v = b/(ktu+eps); zero ktu for next accumulation ----
        for (int j = gtid; j < VV; j += nthr) {
            v[j]  = b_ / (ktu[j] + EPSF);
            ktu[j] = 0.0f;
        }
        if (gtid == 0) scal[0] = 0.0f;   // reset err accumulator
        grid.sync();

        // ---- phase B: Kv per row, u = a/(Kv+eps) (fused in-block) ----
        for (int t = blockIdx.x; t < TT; t += gridDim.x) {
            const float* row = M + (size_t)t * VV;
            float s = 0.0f;
            for (int j = tid; j < VV; j += blockDim.x)
                s += exp2f(row[j] * C2) * v[j];
            const float tot = blockReduceSum(s, sred);
            if (tid == 0) u[t] = a_ / (tot + EPSF);
        }
        grid.sync();

        ++cpt;
        if (cpt >= MAX_ITER) break;
        if (cpt % 50 == 1) {
            // err = sum_j | v[j] * (K^T u_new)[j] - b |
            phaseA(M, u, ktu, gtid, nthr);   // ktu = K^T u_new (reused next iter)
            grid.sync();
            float pe = 0.0f;
            for (int j = gtid; j < VV; j += nthr)
                pe += fabsf(v[j] * ktu[j] - b_);
            const float tot = blockReduceSum(pe, sred);
            if (tid == 0) atomicAdd(&scal[0], tot);
            grid.sync();
            if (tid == 0)
                sbc = __hip_atomic_load(&scal[0], __ATOMIC_RELAXED,
                                        __HIP_MEMORY_SCOPE_AGENT);
            __syncthreads();
            const float err = sbc;
            if (err <= STOPTHR) break;
            haveKtu = true;                  // reuse ktu as next iter's K^T u
        }
    }

    // ---- loss = sum_{t,j} u[t] * K[t,j] * v[j] * M[t,j] ----
    grid.sync();
    for (int t = blockIdx.x; t < TT; t += gridDim.x) {
        const float* row = M + (size_t)t * VV;
        float s = 0.0f;
        for (int j = tid; j < VV; j += blockDim.x) {
            const float m = row[j];
            s += exp2f(m * C2) * v[j] * m;
        }
        const float tot = blockReduceSum(s, sred);
        if (tid == 0) {
            const float ut = __hip_atomic_load(&u[t], __ATOMIC_RELAXED,
                                               __HIP_MEMORY_SCOPE_AGENT);
            atomicAdd(&scal[1], tot * ut);
        }
    }
    grid.sync();
    if (gtid == 0)
        out[0] = __hip_atomic_load(&scal[1], __ATOMIC_RELAXED,
                                   __HIP_MEMORY_SCOPE_AGENT) * W_ECR;
}

extern "C" void kernel_launch(void* const* d_in, const int* in_sizes, int n_in,
                              void* d_out, int out_size, void* d_ws, size_t ws_size,
                              hipStream_t stream) {
    const float* M  = (const float*)d_in[0];
    float* out = (float*)d_out;
    float* ws  = (float*)d_ws;

    // Cooperative launch: grid must be co-resident. Query occupancy (host-side,
    // capture-safe) and cap at 1024 blocks.
    int dev = 0;
    hipGetDevice(&dev);
    int nCU = 0;
    hipDeviceGetAttribute(&nCU, hipDeviceAttributeMultiprocessorCount, dev);
    int blocksPerCU = 0;
    hipOccupancyMaxActiveBlocksPerMultiprocessor(
        &blocksPerCU, (const void*)sinkhorn_ot_kernel, 256, 0);
    if (blocksPerCU < 1) blocksPerCU = 1;
    if (nCU < 1) nCU = 256;
    int grid = blocksPerCU * nCU;
    if (grid > 1024) grid = 1024;

    void* args[] = { (void*)&M, (void*)&ws, (void*)&out };
    hipLaunchCooperativeKernel((void*)sinkhorn_ot_kernel,
                               dim3(grid), dim3(256), args, 0, stream);
}

// Round 2
// 912.062 us; speedup vs baseline: 1.4121x; 1.4121x over previous
//
#include <hip/hip_runtime.h>
#include <hip/hip_cooperative_groups.h>
#include <cstdint>

namespace cg = cooperative_groups;

#define TT 1024
#define VV 50257
#define VP 50264              // VV padded to multiple of 8 (rows 16B-aligned)
#define NJB (VP / 4)          // 12566 ushort4 groups per row
#define TCH 32                // rows per phase-A work item
#define NCH (TT / TCH)        // 32

static constexpr float W_ECR   = 100.0f;
static constexpr int   MAX_ITER = 100;
static constexpr float STOPTHR = 0.005f;
static constexpr float EPSF    = 1e-16f;
// exp(-20*m) = exp2(m * (-20*log2(e)))
static constexpr float C2 = -28.853900817779268f;

__device__ __forceinline__ float bflo(unsigned w) { return __uint_as_float(w << 16); }
__device__ __forceinline__ float bfhi(unsigned w) { return __uint_as_float(w & 0xffff0000u); }

__device__ __forceinline__ float blockReduceSum(float val, float* sred) {
    #pragma unroll
    for (int off = 32; off > 0; off >>= 1)
        val += __shfl_down(val, off, 64);
    const int lane = threadIdx.x & 63;
    const int wid  = threadIdx.x >> 6;
    if (lane == 0) sred[wid] = val;
    __syncthreads();
    float r = (threadIdx.x < (blockDim.x >> 6)) ? sred[threadIdx.x] : 0.0f;
    if (wid == 0) {
        r += __shfl_down(r, 4, 64);
        r += __shfl_down(r, 2, 64);
        r += __shfl_down(r, 1, 64);
    }
    __syncthreads();
    return r;   // valid in thread 0 only
}

// ---- one-time: Kb[t][j] = bf16(exp(-20*M[t][j])), zero-padded columns ----
__global__ __launch_bounds__(512)
void precomp_kernel(const float* __restrict__ M, unsigned short* __restrict__ Kb) {
    const int t = blockIdx.x;
    const float* row = M + (size_t)t * VV;
    unsigned short* orow = Kb + (size_t)t * VP;
    for (int j = threadIdx.x; j < VP; j += blockDim.x) {
        float k = (j < VV) ? exp2f(row[j] * C2) : 0.0f;
        unsigned x = __float_as_uint(k);
        unsigned r = (x + 0x7fffu + ((x >> 16) & 1u)) >> 16;   // RNE f32->bf16
        orow[j] = (unsigned short)r;
    }
}

// Phase A (bf16): ktu[j] += sum_t K[t][j] * u[t]
__device__ __forceinline__ void phaseA_bf(const unsigned short* __restrict__ Kb,
                                          const float* __restrict__ u,
                                          float* __restrict__ ktu,
                                          int gtid, int nthr) {
    constexpr unsigned nitems = (unsigned)NCH * NJB;   // 402,112
    for (unsigned it = (unsigned)gtid; it < nitems; it += (unsigned)nthr) {
        const unsigned c  = it / NJB;          // constant divisor -> magic mul
        const unsigned jb = it - c * NJB;
        const unsigned short* p = Kb + (size_t)(c * TCH) * VP + (size_t)jb * 4;
        const float* up = u + c * TCH;
        float s0 = 0.f, s1 = 0.f, s2 = 0.f, s3 = 0.f;
        #pragma unroll 8
        for (int i = 0; i < TCH; ++i) {
            const uint2 w = *(const uint2*)(p + (size_t)i * VP);
            const float ui = up[i];
            s0 += bflo(w.x) * ui; s1 += bfhi(w.x) * ui;
            s2 += bflo(w.y) * ui; s3 += bfhi(w.y) * ui;
        }
        float* kt = ktu + (size_t)jb * 4;
        atomicAdd(kt + 0, s0); atomicAdd(kt + 1, s1);
        atomicAdd(kt + 2, s2); atomicAdd(kt + 3, s3);
    }
}

// Phase A (fp32 fallback): recompute K from M on the fly
__device__ __forceinline__ void phaseA_f32(const float* __restrict__ M,
                                           const float* __restrict__ u,
                                           float* __restrict__ ktu,
                                           int gtid, int nthr) {
    const unsigned nitems = (unsigned)VV * NCH;
    for (unsigned it = (unsigned)gtid; it < nitems; it += (unsigned)nthr) {
        const unsigned c = it / VV;
        const unsigned j = it - c * VV;
        const float* p  = M + (size_t)(c * TCH) * VV + j;
        const float* up = u + c * TCH;
        float s = 0.0f;
        #pragma unroll 8
        for (int i = 0; i < TCH; ++i)
            s += exp2f(p[(size_t)i * VV] * C2) * up[i];
        atomicAdd(&ktu[j], s);
    }
}

template <bool USEK>
__global__ __launch_bounds__(512, 8)
void sinkhorn_iter(const float* __restrict__ M,
                   const unsigned short* __restrict__ Kb,
                   float* __restrict__ vecws,
                   float* __restrict__ out) {
    cg::grid_group grid = cg::this_grid();

    float* ktu  = vecws;               // VP
    float* v    = vecws + VP;          // VP
    float* u    = vecws + 2 * VP;      // TT
    float* scal = vecws + 2 * VP + TT; // [0]=err, [1]=loss

    const int tid  = threadIdx.x;
    const int gtid = blockIdx.x * blockDim.x + tid;
    const int nthr = gridDim.x * blockDim.x;

    __shared__ float sred[8];
    __shared__ float sbc;

    const float a_ = 1.0f / TT;
    const float b_ = 1.0f / VV;

    // ---- init (ws poisoned 0xAA before every call) ----
    for (int j = gtid; j < VP; j += nthr) ktu[j] = 0.0f;
    for (int t = gtid; t < TT; t += nthr) u[t] = a_;
    if (gtid == 0) { scal[0] = 0.0f; scal[1] = 0.0f; }
    grid.sync();

    bool haveKtu = false;
    int  cpt = 0;
    while (true) {
        // ---- phase A: ktu = K^T u ----
        if (!haveKtu) {
            if constexpr (USEK) phaseA_bf(Kb, u, ktu, gtid, nthr);
            else                phaseA_f32(M, u, ktu, gtid, nthr);
            grid.sync();
        }
        haveKtu = false;

        // ---- phase V: v = b/(ktu+eps); re-zero ktu ----
        for (int j = gtid; j < VP; j += nthr) {
            v[j]   = b_ / (ktu[j] + EPSF);
            ktu[j] = 0.0f;
        }
        if (gtid == 0) scal[0] = 0.0f;
        grid.sync();

        // ---- phase B: u = a/(K v + eps), row per block ----
        for (int t = blockIdx.x; t < TT; t += gridDim.x) {
            float s = 0.0f;
            if constexpr (USEK) {
                const unsigned short* row = Kb + (size_t)t * VP;
                for (int j8 = tid * 8; j8 < VP; j8 += blockDim.x * 8) {
                    const uint4  w  = *(const uint4*)(row + j8);
                    const float4 va = *(const float4*)(v + j8);
                    const float4 vb = *(const float4*)(v + j8 + 4);
                    s += bflo(w.x) * va.x + bfhi(w.x) * va.y
                       + bflo(w.y) * va.z + bfhi(w.y) * va.w
                       + bflo(w.z) * vb.x + bfhi(w.z) * vb.y
                       + bflo(w.w) * vb.z + bfhi(w.w) * vb.w;
                }
            } else {
                const float* row = M + (size_t)t * VV;
                for (int j = tid; j < VV; j += blockDim.x)
                    s += exp2f(row[j] * C2) * v[j];
            }
            const float tot = blockReduceSum(s, sred);
            if (tid == 0) u[t] = a_ / (tot + EPSF);
        }
        grid.sync();

        ++cpt;
        if (cpt >= MAX_ITER) break;
        if (cpt % 50 == 1) {
            // err = sum_{j<VV} | v[j]*(K^T u_new)[j] - b |  (exclude pads!)
            if constexpr (USEK) phaseA_bf(Kb, u, ktu, gtid, nthr);
            else                phaseA_f32(M, u, ktu, gtid, nthr);
            grid.sync();
            float pe = 0.0f;
            for (int j = gtid; j < VV; j += nthr)
                pe += fabsf(v[j] * ktu[j] - b_);
            const float tot = blockReduceSum(pe, sred);
            if (tid == 0) atomicAdd(&scal[0], tot);
            grid.sync();
            if (tid == 0)
                sbc = __hip_atomic_load(&scal[0], __ATOMIC_RELAXED,
                                        __HIP_MEMORY_SCOPE_AGENT);
            __syncthreads();
            if (sbc <= STOPTHR) break;
            haveKtu = true;                 // ktu already = K^T u for next iter
        }
    }

    // ---- loss = sum u_t * exp(-20*M) * v_j * M  (exact fp32 from M) ----
    grid.sync();
    for (int t = blockIdx.x; t < TT; t += gridDim.x) {
        const float* row = M + (size_t)t * VV;
        float s = 0.0f;
        for (int j = tid; j < VV; j += blockDim.x) {
            const float m = row[j];
            s += exp2f(m * C2) * v[j] * m;
        }
        const float tot = blockReduceSum(s, sred);
        if (tid == 0) {
            const float ut = __hip_atomic_load(&u[t], __ATOMIC_RELAXED,
                                               __HIP_MEMORY_SCOPE_AGENT);
            atomicAdd(&scal[1], tot * ut);
        }
    }
    grid.sync();
    if (gtid == 0)
        out[0] = __hip_atomic_load(&scal[1], __ATOMIC_RELAXED,
                                   __HIP_MEMORY_SCOPE_AGENT) * W_ECR;
}

extern "C" void kernel_launch(void* const* d_in, const int* in_sizes, int n_in,
                              void* d_out, int out_size, void* d_ws, size_t ws_size,
                              hipStream_t stream) {
    const float* M = (const float*)d_in[0];
    float* out = (float*)d_out;

    const size_t KBYTES   = (size_t)VP * TT * 2;                 // 102.9 MB
    const size_t VECBYTES = (size_t)(2 * VP + TT + 8) * 4;
    const bool   useK     = (ws_size >= KBYTES + VECBYTES);

    unsigned short* Kb = useK ? (unsigned short*)d_ws : nullptr;
    float* vecws = useK ? (float*)((char*)d_ws + KBYTES) : (float*)d_ws;

    int dev = 0;
    hipGetDevice(&dev);
    int nCU = 0;
    hipDeviceGetAttribute(&nCU, hipDeviceAttributeMultiprocessorCount, dev);
    if (nCU < 1) nCU = 256;

    const void* kfn = useK ? (const void*)sinkhorn_iter<true>
                           : (const void*)sinkhorn_iter<false>;
    int blocksPerCU = 0;
    hipOccupancyMaxActiveBlocksPerMultiprocessor(&blocksPerCU, kfn, 512, 0);
    if (blocksPerCU < 1) blocksPerCU = 1;
    int grid = blocksPerCU * nCU;
    if (grid > TT) grid = TT;   // phase B maps 1 row per block

    if (useK)
        precomp_kernel<<<dim3(TT), dim3(512), 0, stream>>>(M, Kb);

    void* args[] = { (void*)&M, (void*)&Kb, (void*)&vecws, (void*)&out };
    hipLaunchCooperativeKernel((void*)kfn, dim3(grid), dim3(512), args, 0, stream);
}

// Round 4
// 846.064 us; speedup vs baseline: 1.5223x; 1.0780x over previous
//
#include <hip/hip_runtime.h>
#include <hip/hip_cooperative_groups.h>

namespace cg = cooperative_groups;

#define TT   1024
#define VV   50257
#define VP2  50432            // columns padded to 256*197
#define NG   197              // phase-C column groups of 256
#define WIN  12608            // VP2/4, phase-R/loss v window (50.4 KB LDS)
#define NB   256              // workgroups (1 per CU)
#define NTH  512

static constexpr float W_ECR    = 100.0f;
static constexpr int   MAX_ITER = 100;
static constexpr float STOPTHR  = 0.005f;
static constexpr float EPSF     = 1e-16f;
// exp(-20*m) = exp2(m * (-20*log2(e)))
static constexpr float C2 = -28.853900817779268f;

// Persistent device state — fully rewritten on every call (no stale reuse).
__device__ unsigned short g_Kb[(size_t)TT * VP2];   // bf16 K, zero-padded cols
__device__ float          g_u[TT];
__device__ float          g_v[2][VP2];              // double-buffered v
__device__ float          g_scal[4];                // 0=err@1, 1=err@51, 2=loss

__device__ __forceinline__ float bflo(unsigned w) { return __uint_as_float(w << 16); }
__device__ __forceinline__ float bfhi(unsigned w) { return __uint_as_float(w & 0xffff0000u); }
__device__ __forceinline__ unsigned short f2bf(float f) {
    unsigned x = __float_as_uint(f);
    return (unsigned short)((x + 0x7fffu + ((x >> 16) & 1u)) >> 16);  // RNE
}

__device__ __forceinline__ float blockReduceSum512(float val, float* sred) {
    #pragma unroll
    for (int off = 32; off > 0; off >>= 1)
        val += __shfl_down(val, off, 64);
    const int lane = threadIdx.x & 63;
    const int wid  = threadIdx.x >> 6;
    if (lane == 0) sred[wid] = val;
    __syncthreads();
    float r = (threadIdx.x < 8) ? sred[threadIdx.x] : 0.0f;
    if (wid == 0) {
        r += __shfl_down(r, 4, 64);
        r += __shfl_down(r, 2, 64);
        r += __shfl_down(r, 1, 64);
    }
    __syncthreads();
    return r;   // valid in thread 0 only
}

__global__ __launch_bounds__(NTH)
void sinkhorn_all(const float* __restrict__ M, float* __restrict__ out) {
    cg::grid_group grid = cg::this_grid();
    const int tid = threadIdx.x;
    const int bid = blockIdx.x;

    __shared__ float vwin[WIN];        // 50432 B
    __shared__ float su[TT];           // 4096 B
    __shared__ float sA[4 * 128];      // 2048 B
    __shared__ float sB[4 * 128];      // 2048 B
    __shared__ float sred[8];

    const float a_ = 1.0f / TT;
    const float b_ = 1.0f / VV;

    // ---------- phase P: Kb = bf16(exp(-20 M)); init u, scal ----------
    {
        const int t0 = bid * 4;
        #pragma unroll 1
        for (int r = 0; r < 4; ++r) {
            const float* mrow = M + (size_t)(t0 + r) * VV;
            unsigned short* krow = g_Kb + (size_t)(t0 + r) * VP2;
            for (int j = tid; j < VP2; j += NTH)
                krow[j] = (j < VV) ? f2bf(exp2f(mrow[j] * C2)) : (unsigned short)0;
        }
        if (tid < 4) {
            if (bid == 0) g_scal[tid] = 0.0f;
            g_u[t0 + tid] = a_;
        }
    }
    grid.sync();

    const float* vfin = nullptr;
    int it = 1;
    for (;; ++it) {
        // ---------- phase C: s_j = (K^T u)_j ; v_new = b/(s+eps) ----------
        float* vnew = g_v[it & 1];
        const float* vold = g_v[(it - 1) & 1];
        const bool chk = (it == 2) || (it == 52);
        if (bid < NG) {
            su[tid] = g_u[tid]; su[tid + NTH] = g_u[tid + NTH];
            __syncthreads();
            const int ucol = tid & 127;        // 2 adjacent cols per thread
            const int seg  = tid >> 7;         // 4 row-segments of 256
            const unsigned short* base =
                g_Kb + (size_t)(seg * 256) * VP2 + (size_t)bid * 256 + ucol * 2;
            const float* us = su + seg * 256;
            float s0 = 0.0f, s1 = 0.0f;
            #pragma unroll 16
            for (int r = 0; r < 256; ++r) {
                const unsigned w = *(const unsigned*)(base + (size_t)r * VP2);
                const float ur = us[r];
                s0 = fmaf(bflo(w), ur, s0);
                s1 = fmaf(bfhi(w), ur, s1);
            }
            sA[seg * 128 + ucol] = s0;
            sB[seg * 128 + ucol] = s1;
            __syncthreads();
            float ep = 0.0f;
            if (tid < 256) {
                const int uc = tid >> 1;
                float sum = 0.0f;
                #pragma unroll
                for (int s = 0; s < 4; ++s)
                    sum += (tid & 1) ? sB[s * 128 + uc] : sA[s * 128 + uc];
                const int c = bid * 256 + tid;   // (uc*2 + (tid&1)) == tid
                if (c < VV) {
                    if (chk) ep = fabsf(vold[c] * sum - b_);
                    vnew[c] = b_ / (sum + EPSF);
                } else {
                    vnew[c] = 0.0f;
                }
            }
            if (chk) {
                const float tot = blockReduceSum512(ep, sred);
                if (tid == 0) atomicAdd(&g_scal[it == 2 ? 0 : 1], tot);
            }
        }
        grid.sync();

        if (it == 2 &&
            __hip_atomic_load(&g_scal[0], __ATOMIC_RELAXED, __HIP_MEMORY_SCOPE_AGENT)
                <= STOPTHR) { vfin = vold; break; }
        if (it == 52 &&
            __hip_atomic_load(&g_scal[1], __ATOMIC_RELAXED, __HIP_MEMORY_SCOPE_AGENT)
                <= STOPTHR) { vfin = vold; break; }

        // ---------- phase R: u_t = a/((K v)_t + eps), 4 rows/block ----------
        {
            const float* vcur = vnew;
            const int t0 = bid * 4;
            const unsigned short* rbase = g_Kb + (size_t)t0 * VP2;
            float acc0 = 0.f, acc1 = 0.f, acc2 = 0.f, acc3 = 0.f;
            #pragma unroll 1
            for (int w = 0; w < 4; ++w) {
                const int c0 = w * WIN;
                __syncthreads();
                for (int i = tid; i < WIN / 4; i += NTH)
                    *(float4*)(vwin + 4 * i) = *(const float4*)(vcur + c0 + 4 * i);
                __syncthreads();
                #pragma unroll 2
                for (int i = tid * 4; i < WIN; i += NTH * 4) {
                    const float4 va = *(const float4*)(vwin + i);
                    const unsigned short* p = rbase + (size_t)c0 + i;
                    const uint2 k0 = *(const uint2*)(p);
                    const uint2 k1 = *(const uint2*)(p + VP2);
                    const uint2 k2 = *(const uint2*)(p + 2 * (size_t)VP2);
                    const uint2 k3 = *(const uint2*)(p + 3 * (size_t)VP2);
                    acc0 += bflo(k0.x)*va.x + bfhi(k0.x)*va.y + bflo(k0.y)*va.z + bfhi(k0.y)*va.w;
                    acc1 += bflo(k1.x)*va.x + bfhi(k1.x)*va.y + bflo(k1.y)*va.z + bfhi(k1.y)*va.w;
                    acc2 += bflo(k2.x)*va.x + bfhi(k2.x)*va.y + bflo(k2.y)*va.z + bfhi(k2.y)*va.w;
                    acc3 += bflo(k3.x)*va.x + bfhi(k3.x)*va.y + bflo(k3.y)*va.z + bfhi(k3.y)*va.w;
                }
            }
            float t;
            t = blockReduceSum512(acc0, sred); if (tid == 0) g_u[t0 + 0] = a_ / (t + EPSF);
            t = blockReduceSum512(acc1, sred); if (tid == 0) g_u[t0 + 1] = a_ / (t + EPSF);
            t = blockReduceSum512(acc2, sred); if (tid == 0) g_u[t0 + 2] = a_ / (t + EPSF);
            t = blockReduceSum512(acc3, sred); if (tid == 0) g_u[t0 + 3] = a_ / (t + EPSF);
        }
        grid.sync();
        if (it == MAX_ITER) { vfin = vnew; break; }
    }

    // ---------- loss = sum_t u_t * sum_j exp(-20 M) * v_j * M  (exact fp32 M) ----------
    {
        const int t0 = bid * 4;
        float rs0 = 0.f, rs1 = 0.f, rs2 = 0.f, rs3 = 0.f;
        #pragma unroll 1
        for (int w = 0; w < 4; ++w) {
            const int c0 = w * WIN;
            const int cend = (VV - c0 < WIN) ? (VV - c0) : WIN;
            __syncthreads();
            for (int i = tid; i < WIN / 4; i += NTH)
                *(float4*)(vwin + 4 * i) = *(const float4*)(vfin + c0 + 4 * i);
            __syncthreads();
            #pragma unroll 1
            for (int r = 0; r < 4; ++r) {
                const float* mrow = M + (size_t)(t0 + r) * VV + c0;
                float s = 0.0f;
                for (int j = tid; j < cend; j += NTH) {
                    const float m = mrow[j];
                    s = fmaf(exp2f(m * C2) * vwin[j], m, s);
                }
                if (r == 0) rs0 += s; else if (r == 1) rs1 += s;
                else if (r == 2) rs2 += s; else rs3 += s;
            }
        }
        float part = 0.0f, t;
        t = blockReduceSum512(rs0, sred); if (tid == 0) part += t * g_u[t0 + 0];
        t = blockReduceSum512(rs1, sred); if (tid == 0) part += t * g_u[t0 + 1];
        t = blockReduceSum512(rs2, sred); if (tid == 0) part += t * g_u[t0 + 2];
        t = blockReduceSum512(rs3, sred); if (tid == 0) part += t * g_u[t0 + 3];
        if (tid == 0) atomicAdd(&g_scal[2], part);
    }
    grid.sync();
    if (bid == 0 && tid == 0)
        out[0] = __hip_atomic_load(&g_scal[2], __ATOMIC_RELAXED,
                                   __HIP_MEMORY_SCOPE_AGENT) * W_ECR;
}

extern "C" void kernel_launch(void* const* d_in, const int* in_sizes, int n_in,
                              void* d_out, int out_size, void* d_ws, size_t ws_size,
                              hipStream_t stream) {
    const float* M = (const float*)d_in[0];
    float* out = (float*)d_out;
    (void)d_ws; (void)ws_size; (void)in_sizes; (void)n_in; (void)out_size;

    void* args[] = { (void*)&M, (void*)&out };
    // 256 blocks (1/CU on 256-CU MI355X) x 512 threads; 58.7 KB LDS/block
    // -> trivially co-resident for the cooperative launch.
    hipLaunchCooperativeKernel((void*)sinkhorn_all, dim3(NB), dim3(NTH),
                               args, 0, stream);
}

// Round 5
// 692.424 us; speedup vs baseline: 1.8601x; 1.2219x over previous
//
#include <hip/hip_runtime.h>
#include <hip/hip_cooperative_groups.h>

namespace cg = cooperative_groups;

#define TT   1024
#define VV   50257
#define VP2  50432            // columns padded to 256*197
#define NG   197              // phase-C column groups of 256
#define NU   (VP2 / 4)        // 12608 uints (4 fp8) per row
#define WIN  12608            // VP2/4, phase-R/loss v window (50.4 KB LDS)
#define NB   256              // workgroups (1 per CU)
#define NTH  512

static constexpr float W_ECR    = 100.0f;
static constexpr int   MAX_ITER = 100;
static constexpr float STOPTHR  = 0.005f;
static constexpr float EPSF     = 1e-16f;
// exp(-20*m) = exp2(m * (-20*log2(e)))
static constexpr float C2 = -28.853900817779268f;
// K stored as e4m3(K * 2^8): max 256 < 448, subnormal flush only for K < ~2^-17
static constexpr float INVSCALE = 1.0f / 256.0f;

typedef float f2 __attribute__((ext_vector_type(2)));

// Persistent device state — fully rewritten on every call (no stale reuse).
__device__ unsigned g_K8u[(size_t)TT * NU];   // fp8-e4m3 K*256, zero-padded cols
__device__ float    g_u[TT];
__device__ float    g_v[2][VP2];              // double-buffered v
__device__ float    g_scal[4];                // 0=err@1, 1=err@51, 2=loss

__device__ __forceinline__ float blockReduceSum512(float val, float* sred) {
    #pragma unroll
    for (int off = 32; off > 0; off >>= 1)
        val += __shfl_down(val, off, 64);
    const int lane = threadIdx.x & 63;
    const int wid  = threadIdx.x >> 6;
    if (lane == 0) sred[wid] = val;
    __syncthreads();
    float r = (threadIdx.x < 8) ? sred[threadIdx.x] : 0.0f;
    if (wid == 0) {
        r += __shfl_down(r, 4, 64);
        r += __shfl_down(r, 2, 64);
        r += __shfl_down(r, 1, 64);
    }
    __syncthreads();
    return r;   // valid in thread 0 only
}

__global__ __launch_bounds__(NTH)
void sinkhorn_all(const float* __restrict__ M, float* __restrict__ out) {
    cg::grid_group grid = cg::this_grid();
    const int tid = threadIdx.x;
    const int bid = blockIdx.x;

    __shared__ float vwin[WIN];        // 50432 B
    __shared__ float su[TT];           // 4096 B
    __shared__ float sC[8 * 256];      // 8192 B  phase-C partials
    __shared__ float sred[8];

    const float a_ = 1.0f / TT;
    const float b_ = 1.0f / VV;

    // ---------- phase P: K8 = e4m3(exp(-20 M) * 256); init u, scal ----------
    {
        const int t0 = bid * 4;
        #pragma unroll 1
        for (int r = 0; r < 4; ++r) {
            const float* mrow = M + (size_t)(t0 + r) * VV;
            unsigned* krow = g_K8u + (size_t)(t0 + r) * NU;
            for (int j4 = tid; j4 < NU; j4 += NTH) {
                const int j = j4 * 4;
                float f0 = (j + 0 < VV) ? exp2f(fmaf(mrow[j + 0], C2, 8.0f)) : 0.0f;
                float f1 = (j + 1 < VV) ? exp2f(fmaf(mrow[j + 1], C2, 8.0f)) : 0.0f;
                float f2v = (j + 2 < VV) ? exp2f(fmaf(mrow[j + 2], C2, 8.0f)) : 0.0f;
                float f3 = (j + 3 < VV) ? exp2f(fmaf(mrow[j + 3], C2, 8.0f)) : 0.0f;
                int w = __builtin_amdgcn_cvt_pk_fp8_f32(f0, f1, 0, false);
                w = __builtin_amdgcn_cvt_pk_fp8_f32(f2v, f3, w, true);
                krow[j4] = (unsigned)w;
            }
        }
        if (tid < 4) {
            if (bid == 0) g_scal[tid] = 0.0f;
            g_u[t0 + tid] = a_;
        }
    }
    grid.sync();

    const float* vfin = nullptr;
    int it = 1;
    for (;; ++it) {
        // ---------- phase C: s_j = (K^T u)_j ; v_new = b/(s+eps) ----------
        float* vnew = g_v[it & 1];
        const float* vold = g_v[(it - 1) & 1];
        const bool chk = (it == 2) || (it == 52);
        if (bid < NG) {
            su[tid] = g_u[tid]; su[tid + NTH] = g_u[tid + NTH];
            __syncthreads();
            const int cq  = tid & 63;          // 4 adjacent cols per thread
            const int seg = tid >> 6;          // 8 row-segments of 128
            const unsigned* base =
                g_K8u + (size_t)(seg * 128) * NU + bid * 64 + cq;
            const float* us = su + seg * 128;
            float s0 = 0.f, s1 = 0.f, s2 = 0.f, s3 = 0.f;
            #pragma unroll 16
            for (int r = 0; r < 128; ++r) {
                const unsigned w = base[(size_t)r * NU];
                const f2 lo = __builtin_amdgcn_cvt_pk_f32_fp8((int)w, false);
                const f2 hi = __builtin_amdgcn_cvt_pk_f32_fp8((int)w, true);
                const float ur = us[r];
                s0 = fmaf(lo.x, ur, s0);
                s1 = fmaf(lo.y, ur, s1);
                s2 = fmaf(hi.x, ur, s2);
                s3 = fmaf(hi.y, ur, s3);
            }
            float* sc = sC + seg * 256 + cq * 4;
            sc[0] = s0; sc[1] = s1; sc[2] = s2; sc[3] = s3;
            __syncthreads();
            float ep = 0.0f;
            if (tid < 256) {
                float sum = 0.0f;
                #pragma unroll
                for (int s = 0; s < 8; ++s) sum += sC[s * 256 + tid];
                const int c = bid * 256 + tid;
                if (c < VV) {
                    const float sv = sum * INVSCALE;
                    if (chk) ep = fabsf(vold[c] * sv - b_);
                    vnew[c] = b_ / (sv + EPSF);
                } else {
                    vnew[c] = 0.0f;
                }
            }
            if (chk) {
                const float tot = blockReduceSum512(ep, sred);
                if (tid == 0) atomicAdd(&g_scal[it == 2 ? 0 : 1], tot);
            }
        }
        grid.sync();

        if (it == 2 &&
            __hip_atomic_load(&g_scal[0], __ATOMIC_RELAXED, __HIP_MEMORY_SCOPE_AGENT)
                <= STOPTHR) { vfin = vold; break; }
        if (it == 52 &&
            __hip_atomic_load(&g_scal[1], __ATOMIC_RELAXED, __HIP_MEMORY_SCOPE_AGENT)
                <= STOPTHR) { vfin = vold; break; }

        // ---------- phase R: u_t = a/((K v)_t + eps), 4 rows/block ----------
        {
            const float* vcur = vnew;
            const int t0 = bid * 4;
            const unsigned char* rbase =
                (const unsigned char*)g_K8u + (size_t)t0 * VP2;
            float acc0 = 0.f, acc1 = 0.f, acc2 = 0.f, acc3 = 0.f;
            #pragma unroll 1
            for (int w4 = 0; w4 < 4; ++w4) {
                const int c0 = w4 * WIN;
                __syncthreads();
                for (int i = tid; i < WIN / 4; i += NTH)
                    *(float4*)(vwin + 4 * i) = *(const float4*)(vcur + c0 + 4 * i);
                __syncthreads();
                #pragma unroll 2
                for (int i = tid * 8; i < WIN; i += NTH * 8) {
                    const float4 va = *(const float4*)(vwin + i);
                    const float4 vb = *(const float4*)(vwin + i + 4);
                    const size_t off = (size_t)c0 + i;
                    const uint2 k0 = *(const uint2*)(rbase + off);
                    const uint2 k1 = *(const uint2*)(rbase + off + VP2);
                    const uint2 k2 = *(const uint2*)(rbase + off + 2 * (size_t)VP2);
                    const uint2 k3 = *(const uint2*)(rbase + off + 3 * (size_t)VP2);
                    {
                        const f2 p0 = __builtin_amdgcn_cvt_pk_f32_fp8((int)k0.x, false);
                        const f2 p1 = __builtin_amdgcn_cvt_pk_f32_fp8((int)k0.x, true);
                        const f2 p2 = __builtin_amdgcn_cvt_pk_f32_fp8((int)k0.y, false);
                        const f2 p3 = __builtin_amdgcn_cvt_pk_f32_fp8((int)k0.y, true);
                        acc0 = fmaf(p0.x, va.x, acc0); acc0 = fmaf(p0.y, va.y, acc0);
                        acc0 = fmaf(p1.x, va.z, acc0); acc0 = fmaf(p1.y, va.w, acc0);
                        acc0 = fmaf(p2.x, vb.x, acc0); acc0 = fmaf(p2.y, vb.y, acc0);
                        acc0 = fmaf(p3.x, vb.z, acc0); acc0 = fmaf(p3.y, vb.w, acc0);
                    }
                    {
                        const f2 p0 = __builtin_amdgcn_cvt_pk_f32_fp8((int)k1.x, false);
                        const f2 p1 = __builtin_amdgcn_cvt_pk_f32_fp8((int)k1.x, true);
                        const f2 p2 = __builtin_amdgcn_cvt_pk_f32_fp8((int)k1.y, false);
                        const f2 p3 = __builtin_amdgcn_cvt_pk_f32_fp8((int)k1.y, true);
                        acc1 = fmaf(p0.x, va.x, acc1); acc1 = fmaf(p0.y, va.y, acc1);
                        acc1 = fmaf(p1.x, va.z, acc1); acc1 = fmaf(p1.y, va.w, acc1);
                        acc1 = fmaf(p2.x, vb.x, acc1); acc1 = fmaf(p2.y, vb.y, acc1);
                        acc1 = fmaf(p3.x, vb.z, acc1); acc1 = fmaf(p3.y, vb.w, acc1);
                    }
                    {
                        const f2 p0 = __builtin_amdgcn_cvt_pk_f32_fp8((int)k2.x, false);
                        const f2 p1 = __builtin_amdgcn_cvt_pk_f32_fp8((int)k2.x, true);
                        const f2 p2 = __builtin_amdgcn_cvt_pk_f32_fp8((int)k2.y, false);
                        const f2 p3 = __builtin_amdgcn_cvt_pk_f32_fp8((int)k2.y, true);
                        acc2 = fmaf(p0.x, va.x, acc2); acc2 = fmaf(p0.y, va.y, acc2);
                        acc2 = fmaf(p1.x, va.z, acc2); acc2 = fmaf(p1.y, va.w, acc2);
                        acc2 = fmaf(p2.x, vb.x, acc2); acc2 = fmaf(p2.y, vb.y, acc2);
                        acc2 = fmaf(p3.x, vb.z, acc2); acc2 = fmaf(p3.y, vb.w, acc2);
                    }
                    {
                        const f2 p0 = __builtin_amdgcn_cvt_pk_f32_fp8((int)k3.x, false);
                        const f2 p1 = __builtin_amdgcn_cvt_pk_f32_fp8((int)k3.x, true);
                        const f2 p2 = __builtin_amdgcn_cvt_pk_f32_fp8((int)k3.y, false);
                        const f2 p3 = __builtin_amdgcn_cvt_pk_f32_fp8((int)k3.y, true);
                        acc3 = fmaf(p0.x, va.x, acc3); acc3 = fmaf(p0.y, va.y, acc3);
                        acc3 = fmaf(p1.x, va.z, acc3); acc3 = fmaf(p1.y, va.w, acc3);
                        acc3 = fmaf(p2.x, vb.x, acc3); acc3 = fmaf(p2.y, vb.y, acc3);
                        acc3 = fmaf(p3.x, vb.z, acc3); acc3 = fmaf(p3.y, vb.w, acc3);
                    }
                }
            }
            float t;
            t = blockReduceSum512(acc0, sred); if (tid == 0) g_u[t0 + 0] = a_ / (t * INVSCALE + EPSF);
            t = blockReduceSum512(acc1, sred); if (tid == 0) g_u[t0 + 1] = a_ / (t * INVSCALE + EPSF);
            t = blockReduceSum512(acc2, sred); if (tid == 0) g_u[t0 + 2] = a_ / (t * INVSCALE + EPSF);
            t = blockReduceSum512(acc3, sred); if (tid == 0) g_u[t0 + 3] = a_ / (t * INVSCALE + EPSF);
        }
        grid.sync();
        if (it == MAX_ITER) { vfin = vnew; break; }
    }

    // ---------- loss = sum_t u_t * sum_j exp(-20 M) * v_j * M  (exact fp32 M) ----------
    {
        const int t0 = bid * 4;
        float rs0 = 0.f, rs1 = 0.f, rs2 = 0.f, rs3 = 0.f;
        #pragma unroll 1
        for (int w4 = 0; w4 < 4; ++w4) {
            const int c0 = w4 * WIN;
            const int cend = (VV - c0 < WIN) ? (VV - c0) : WIN;
            __syncthreads();
            for (int i = tid; i < WIN / 4; i += NTH)
                *(float4*)(vwin + 4 * i) = *(const float4*)(vfin + c0 + 4 * i);
            __syncthreads();
            #pragma unroll 1
            for (int r = 0; r < 4; ++r) {
                const float* mrow = M + (size_t)(t0 + r) * VV + c0;
                float s = 0.0f;
                for (int j = tid; j < cend; j += NTH) {
                    const float m = mrow[j];
                    s = fmaf(exp2f(m * C2) * vwin[j], m, s);
                }
                if (r == 0) rs0 += s; else if (r == 1) rs1 += s;
                else if (r == 2) rs2 += s; else rs3 += s;
            }
        }
        float part = 0.0f, t;
        t = blockReduceSum512(rs0, sred); if (tid == 0) part += t * g_u[t0 + 0];
        t = blockReduceSum512(rs1, sred); if (tid == 0) part += t * g_u[t0 + 1];
        t = blockReduceSum512(rs2, sred); if (tid == 0) part += t * g_u[t0 + 2];
        t = blockReduceSum512(rs3, sred); if (tid == 0) part += t * g_u[t0 + 3];
        if (tid == 0) atomicAdd(&g_scal[2], part);
    }
    grid.sync();
    if (bid == 0 && tid == 0)
        out[0] = __hip_atomic_load(&g_scal[2], __ATOMIC_RELAXED,
                                   __HIP_MEMORY_SCOPE_AGENT) * W_ECR;
}

extern "C" void kernel_launch(void* const* d_in, const int* in_sizes, int n_in,
                              void* d_out, int out_size, void* d_ws, size_t ws_size,
                              hipStream_t stream) {
    const float* M = (const float*)d_in[0];
    float* out = (float*)d_out;
    (void)d_ws; (void)ws_size; (void)in_sizes; (void)n_in; (void)out_size;

    void* args[] = { (void*)&M, (void*)&out };
    // 256 blocks (1/CU on 256-CU MI355X) x 512 threads; ~62.8 KB LDS/block
    // -> trivially co-resident for the cooperative launch.
    hipLaunchCooperativeKernel((void*)sinkhorn_all, dim3(NB), dim3(NTH),
                               args, 0, stream);
}